// Round 1
// baseline (108.517 us; speedup 1.0000x reference)
//
#include <hip/hip_runtime.h>

#define Bn 8
#define Sn 2048
#define Cn 768
#define Hn 64

typedef __attribute__((ext_vector_type(8))) short bf16x8;
typedef __attribute__((ext_vector_type(4))) float f32x4;

__device__ __forceinline__ unsigned short f2bf(float x) {
  unsigned int u = __builtin_bit_cast(unsigned int, x);
  u += 0x7FFFu + ((u >> 16) & 1u);
  return (unsigned short)(u >> 16);
}

// ---------------- kernel 0: W convert + transpose: W[c][h] f32 -> Wt[h][c] bf16 ----------------
__global__ __launch_bounds__(256) void wconv(const float* __restrict__ Wq,
                                             const float* __restrict__ Wk,
                                             const float* __restrict__ Wv,
                                             unsigned short* __restrict__ Wt) {
  int idx = blockIdx.x * 256 + threadIdx.x;      // 3*768*64 = 147456 total
  int mat = idx / (Cn * Hn);
  int rem = idx - mat * (Cn * Hn);
  int c = rem / Hn, h = rem - c * Hn;
  const float* W = (mat == 0) ? Wq : (mat == 1) ? Wk : Wv;
  Wt[mat * (Hn * Cn) + h * Cn + c] = f2bf(W[rem]);
}

// ---------------- kernel 1: projections  Y = (X @ W + b) [* scale for q] ----------------
// grid: 768 blocks (256 per matrix), 64 rows per block, 4 waves x 16 rows
__global__ __launch_bounds__(256) void proj(const float* __restrict__ q,
                                            const float* __restrict__ k,
                                            const float* __restrict__ v,
                                            const float* __restrict__ bq,
                                            const float* __restrict__ bk,
                                            const float* __restrict__ bv,
                                            const unsigned short* __restrict__ Wt,
                                            unsigned short* __restrict__ qi,
                                            unsigned short* __restrict__ ki,
                                            unsigned short* __restrict__ vi) {
  const int mat  = blockIdx.x >> 8;
  const int row0 = (blockIdx.x & 255) * 64;
  const float* X    = (mat == 0) ? q  : (mat == 1) ? k  : v;
  const float* bias = (mat == 0) ? bq : (mat == 1) ? bk : bv;
  unsigned short* Y = (mat == 0) ? qi : (mat == 1) ? ki : vi;
  const unsigned short* Wm = Wt + mat * (Hn * Cn);
  const float scale = (mat == 0) ? 0.03608439182435161f : 1.0f;  // 1/sqrt(768) folded into qi

  __shared__ __align__(16) unsigned char Xs[64 * 128];  // [64 rows][64 bf16], xor-swizzled
  __shared__ __align__(16) unsigned char Ws[64 * 128];  // [64 cols][64 bf16], xor-swizzled

  const int tid  = threadIdx.x;
  const int lane = tid & 63;
  const int w    = tid >> 6;
  const int col  = lane & 15;
  const int grp  = lane >> 4;

  f32x4 acc[4] = {};

  for (int kc = 0; kc < 12; ++kc) {
    __syncthreads();
    // stage X tile: 64 rows x 64 f32 -> bf16 in LDS
#pragma unroll
    for (int i = 0; i < 4; ++i) {
      int f4 = tid + i * 256;
      int r  = f4 >> 4;
      int c4 = f4 & 15;
      float4 xv = *(const float4*)(X + (size_t)(row0 + r) * Cn + kc * 64 + c4 * 4);
      ushort4 hv;
      hv.x = f2bf(xv.x); hv.y = f2bf(xv.y); hv.z = f2bf(xv.z); hv.w = f2bf(xv.w);
      *(ushort4*)(Xs + r * 128 + ((c4 * 8) ^ ((r & 7) << 4))) = hv;
    }
    // stage Wt tile: 64 cols x 64 bf16
    {
      int r = tid >> 2;
      int p = tid & 3;
      const uint4* src = (const uint4*)(Wm + (size_t)r * Cn + kc * 64);
      uint4 a  = src[p * 2];
      uint4 b2 = src[p * 2 + 1];
      *(uint4*)(Ws + r * 128 + ((p * 32) ^ ((r & 7) << 4)))        = a;
      *(uint4*)(Ws + r * 128 + (((p * 32) + 16) ^ ((r & 7) << 4))) = b2;
    }
    __syncthreads();
    // MFMA: wave w computes rows w*16..w*16+15 x 64 cols
    const int rloc = w * 16 + col;
#pragma unroll
    for (int ks = 0; ks < 2; ++ks) {
      bf16x8 a = *(const bf16x8*)(Xs + rloc * 128 + ((ks * 64 + grp * 16) ^ ((rloc & 7) << 4)));
#pragma unroll
      for (int nf = 0; nf < 4; ++nf) {
        int wr = nf * 16 + col;
        bf16x8 bfr = *(const bf16x8*)(Ws + wr * 128 + ((ks * 64 + grp * 16) ^ ((wr & 7) << 4)));
        acc[nf] = __builtin_amdgcn_mfma_f32_16x16x32_bf16(a, bfr, acc[nf], 0, 0, 0);
      }
    }
  }
  // epilogue: D layout col = lane&15, row = grp*4 + reg
#pragma unroll
  for (int nf = 0; nf < 4; ++nf) {
    int h = nf * 16 + col;
    float bv = bias[h];
#pragma unroll
    for (int r2 = 0; r2 < 4; ++r2) {
      int row = row0 + w * 16 + grp * 4 + r2;
      Y[(size_t)row * Hn + h] = f2bf((acc[nf][r2] + bv) * scale);
    }
  }
}

// ---------------- kernel 2: flash attention ----------------
// grid: B * (S/64) = 256 blocks, 4 waves, each wave owns 16 q-rows; KV tiles of 64
__global__ __launch_bounds__(256) void attn(const unsigned short* __restrict__ qi,
                                            const unsigned short* __restrict__ ki,
                                            const unsigned short* __restrict__ vi,
                                            float* __restrict__ out) {
  const int b  = blockIdx.x >> 5;
  const int s0 = (blockIdx.x & 31) * 64;
  const unsigned short* Qb = qi + ((size_t)b * Sn + s0) * Hn;
  const unsigned short* Kb = ki + (size_t)b * Sn * Hn;
  const unsigned short* Vb = vi + (size_t)b * Sn * Hn;

  __shared__ __align__(16) unsigned char Ks[64 * 128];       // [key][dim] bf16, swizzled
  __shared__ __align__(16) unsigned char Vt[64 * 128];       // [dim][key] bf16, swizzled
  __shared__ __align__(16) unsigned char Ps[4 * 16 * 128];   // per-wave [16 q][64 key] bf16

  const int tid  = threadIdx.x;
  const int lane = tid & 63;
  const int w    = tid >> 6;
  const int col  = lane & 15;
  const int grp  = lane >> 4;

  // Q fragments in registers (scale already folded into qi)
  bf16x8 qa[2];
#pragma unroll
  for (int ks2 = 0; ks2 < 2; ++ks2)
    qa[ks2] = *(const bf16x8*)(Qb + (size_t)(w * 16 + col) * Hn + ks2 * 32 + grp * 8);

  f32x4 acc[4] = {};
  float m[4], l[4];
#pragma unroll
  for (int r = 0; r < 4; ++r) { m[r] = -1e30f; l[r] = 0.0f; }

  for (int t = 0; t < Sn / 64; ++t) {
    const unsigned short* Kt = Kb + t * 64 * Hn;
    const unsigned short* Vg = Vb + t * 64 * Hn;
    __syncthreads();  // previous tile fully consumed
    // stage K rows (8KB)
    {
      int kr = tid >> 2, p = tid & 3;
      const uint4* src = (const uint4*)(Kt + kr * Hn);
      uint4 a  = src[p * 2];
      uint4 b2 = src[p * 2 + 1];
      *(uint4*)(Ks + kr * 128 + ((p * 32) ^ ((kr & 7) << 4)))        = a;
      *(uint4*)(Ks + kr * 128 + (((p * 32) + 16) ^ ((kr & 7) << 4))) = b2;
    }
    // stage V transposed: thread reads key-pair x 8 dims, writes packed b32 columns
    {
      int kp = tid >> 3;   // key pair 0..31
      int dg = tid & 7;    // dim group
      uint4 v0 = *(const uint4*)(Vg + (2 * kp) * Hn + dg * 8);
      uint4 v1 = *(const uint4*)(Vg + (2 * kp + 1) * Hn + dg * 8);
      const unsigned short* a0 = (const unsigned short*)&v0;
      const unsigned short* a1 = (const unsigned short*)&v1;
#pragma unroll
      for (int j0 = 0; j0 < 8; ++j0) {
        int j = (j0 + dg) & 7;           // rotate to spread banks
        int d = dg * 8 + j;
        unsigned int pk = (unsigned int)a0[j] | ((unsigned int)a1[j] << 16);
        *(unsigned int*)(Vt + d * 128 + ((4 * kp) ^ ((d & 7) << 4))) = pk;
      }
    }
    __syncthreads();
    // S = Q K^T  (16 q x 64 keys per wave)
    f32x4 sf[4] = {};
#pragma unroll
    for (int ks2 = 0; ks2 < 2; ++ks2) {
#pragma unroll
      for (int nf = 0; nf < 4; ++nf) {
        int kr = nf * 16 + col;
        bf16x8 bfr = *(const bf16x8*)(Ks + kr * 128 + ((ks2 * 64 + grp * 16) ^ ((kr & 7) << 4)));
        sf[nf] = __builtin_amdgcn_mfma_f32_16x16x32_bf16(qa[ks2], bfr, sf[nf], 0, 0, 0);
      }
    }
    // online softmax (rows grp*4+r; reduce across the 16 lanes of the group)
    float mn[4], fs[4];
#pragma unroll
    for (int r = 0; r < 4; ++r) {
      float mx = fmaxf(fmaxf(sf[0][r], sf[1][r]), fmaxf(sf[2][r], sf[3][r]));
#pragma unroll
      for (int off = 1; off < 16; off <<= 1)
        mx = fmaxf(mx, __shfl_xor(mx, off, 64));
      mn[r] = fmaxf(m[r], mx);
      fs[r] = __expf(m[r] - mn[r]);
      m[r]  = mn[r];
    }
#pragma unroll
    for (int nf = 0; nf < 4; ++nf)
#pragma unroll
      for (int r = 0; r < 4; ++r)
        sf[nf][r] = __expf(sf[nf][r] - mn[r]);
#pragma unroll
    for (int r = 0; r < 4; ++r) {
      float sm = sf[0][r] + sf[1][r] + sf[2][r] + sf[3][r];
#pragma unroll
      for (int off = 1; off < 16; off <<= 1)
        sm += __shfl_xor(sm, off, 64);
      l[r] = l[r] * fs[r] + sm;
    }
    // rescale O, write P (bf16) to per-wave LDS
#pragma unroll
    for (int nf = 0; nf < 4; ++nf) {
#pragma unroll
      for (int r = 0; r < 4; ++r) {
        acc[nf][r] *= fs[r];
        int prow = grp * 4 + r;
        int key  = nf * 16 + col;
        *(unsigned short*)(Ps + w * 2048 + prow * 128 + ((key * 2) ^ ((prow & 7) << 4))) =
            f2bf(sf[nf][r]);
      }
    }
    __syncthreads();
    // O += P V
#pragma unroll
    for (int kk = 0; kk < 2; ++kk) {
      bf16x8 pa = *(const bf16x8*)(Ps + w * 2048 + col * 128 +
                                   ((kk * 64 + grp * 16) ^ ((col & 7) << 4)));
#pragma unroll
      for (int nf = 0; nf < 4; ++nf) {
        int dr = nf * 16 + col;
        bf16x8 bv = *(const bf16x8*)(Vt + dr * 128 + ((kk * 64 + grp * 16) ^ ((dr & 7) << 4)));
        acc[nf] = __builtin_amdgcn_mfma_f32_16x16x32_bf16(pa, bv, acc[nf], 0, 0, 0);
      }
    }
  }
  // epilogue: out = acc / l  (fp32 output)
#pragma unroll
  for (int nf = 0; nf < 4; ++nf) {
#pragma unroll
    for (int r = 0; r < 4; ++r) {
      int row = s0 + w * 16 + grp * 4 + r;
      out[((size_t)b * Sn + row) * Hn + nf * 16 + col] = acc[nf][r] / l[r];
    }
  }
}

extern "C" void kernel_launch(void* const* d_in, const int* in_sizes, int n_in,
                              void* d_out, int out_size, void* d_ws, size_t ws_size,
                              hipStream_t stream) {
  const float* q  = (const float*)d_in[0];
  const float* k  = (const float*)d_in[1];
  const float* v  = (const float*)d_in[2];
  const float* Wq = (const float*)d_in[3];
  const float* bq = (const float*)d_in[4];
  const float* Wk = (const float*)d_in[5];
  const float* bk = (const float*)d_in[6];
  const float* Wv = (const float*)d_in[7];
  const float* bv = (const float*)d_in[8];
  float* out = (float*)d_out;

  unsigned short* Wt = (unsigned short*)d_ws;            // [3][64][768] bf16
  unsigned short* qi = Wt + 3 * Hn * Cn;                 // [8*2048][64] bf16 (pre-scaled)
  unsigned short* ki = qi + (size_t)Bn * Sn * Hn;
  unsigned short* vi = ki + (size_t)Bn * Sn * Hn;

  wconv<<<dim3((3 * Cn * Hn) / 256), dim3(256), 0, stream>>>(Wq, Wk, Wv, Wt);
  proj<<<dim3(768), dim3(256), 0, stream>>>(q, k, v, bq, bk, bv, Wt, qi, ki, vi);
  attn<<<dim3(Bn * (Sn / 64)), dim3(256), 0, stream>>>(qi, ki, vi, out);
}

// Round 2
// 87.748 us; speedup vs baseline: 1.2367x; 1.2367x over previous
//
#include <hip/hip_runtime.h>

#define Bn 8
#define Sn 2048
#define Cn 768
#define Hn 64
#define BS (Bn * Sn)

typedef __attribute__((ext_vector_type(8))) short bf16x8;
typedef __attribute__((ext_vector_type(4))) float f32x4;

__device__ __forceinline__ unsigned short f2bf(float x) {
  unsigned int u = __builtin_bit_cast(unsigned int, x);
  u += 0x7FFFu + ((u >> 16) & 1u);
  return (unsigned short)(u >> 16);
}

// ---------------- kernel 0: W convert + transpose: W[c][h] f32 -> Wt[h][c] bf16 ----------------
__global__ __launch_bounds__(256) void wconv(const float* __restrict__ Wq,
                                             const float* __restrict__ Wk,
                                             const float* __restrict__ Wv,
                                             unsigned short* __restrict__ Wt) {
  int idx = blockIdx.x * 256 + threadIdx.x;      // 3*768*64 = 147456 total
  int mat = idx / (Cn * Hn);
  int rem = idx - mat * (Cn * Hn);
  int c = rem / Hn, h = rem - c * Hn;
  const float* W = (mat == 0) ? Wq : (mat == 1) ? Wk : Wv;
  Wt[mat * (Hn * Cn) + h * Cn + c] = f2bf(W[rem]);
}

// ---------------- kernel 1: projections  Y = (X @ W + b) [* scale for q] ----------------
__global__ __launch_bounds__(256) void proj(const float* __restrict__ q,
                                            const float* __restrict__ k,
                                            const float* __restrict__ v,
                                            const float* __restrict__ bq,
                                            const float* __restrict__ bk,
                                            const float* __restrict__ bv,
                                            const unsigned short* __restrict__ Wt,
                                            unsigned short* __restrict__ qi,
                                            unsigned short* __restrict__ ki,
                                            unsigned short* __restrict__ vi) {
  const int mat  = blockIdx.x >> 8;
  const int row0 = (blockIdx.x & 255) * 64;
  const float* X    = (mat == 0) ? q  : (mat == 1) ? k  : v;
  const float* bias = (mat == 0) ? bq : (mat == 1) ? bk : bv;
  unsigned short* Y = (mat == 0) ? qi : (mat == 1) ? ki : vi;
  const unsigned short* Wm = Wt + mat * (Hn * Cn);
  const float scale = (mat == 0) ? 0.03608439182435161f : 1.0f;  // 1/sqrt(768) folded into qi

  __shared__ __align__(16) unsigned char Xs[64 * 128];
  __shared__ __align__(16) unsigned char Ws[64 * 128];

  const int tid  = threadIdx.x;
  const int lane = tid & 63;
  const int w    = tid >> 6;
  const int col  = lane & 15;
  const int grp  = lane >> 4;

  f32x4 acc[4] = {};

  for (int kc = 0; kc < 12; ++kc) {
    __syncthreads();
#pragma unroll
    for (int i = 0; i < 4; ++i) {
      int f4 = tid + i * 256;
      int r  = f4 >> 4;
      int c4 = f4 & 15;
      float4 xv = *(const float4*)(X + (size_t)(row0 + r) * Cn + kc * 64 + c4 * 4);
      ushort4 hv;
      hv.x = f2bf(xv.x); hv.y = f2bf(xv.y); hv.z = f2bf(xv.z); hv.w = f2bf(xv.w);
      *(ushort4*)(Xs + r * 128 + ((c4 * 8) ^ ((r & 7) << 4))) = hv;
    }
    {
      int r = tid >> 2;
      int p = tid & 3;
      const uint4* src = (const uint4*)(Wm + (size_t)r * Cn + kc * 64);
      uint4 a  = src[p * 2];
      uint4 b2 = src[p * 2 + 1];
      *(uint4*)(Ws + r * 128 + ((p * 32) ^ ((r & 7) << 4)))        = a;
      *(uint4*)(Ws + r * 128 + (((p * 32) + 16) ^ ((r & 7) << 4))) = b2;
    }
    __syncthreads();
    const int rloc = w * 16 + col;
#pragma unroll
    for (int ks = 0; ks < 2; ++ks) {
      bf16x8 a = *(const bf16x8*)(Xs + rloc * 128 + ((ks * 64 + grp * 16) ^ ((rloc & 7) << 4)));
#pragma unroll
      for (int nf = 0; nf < 4; ++nf) {
        int wr = nf * 16 + col;
        bf16x8 bfr = *(const bf16x8*)(Ws + wr * 128 + ((ks * 64 + grp * 16) ^ ((wr & 7) << 4)));
        acc[nf] = __builtin_amdgcn_mfma_f32_16x16x32_bf16(a, bfr, acc[nf], 0, 0, 0);
      }
    }
  }
#pragma unroll
  for (int nf = 0; nf < 4; ++nf) {
    int h = nf * 16 + col;
    float bv = bias[h];
#pragma unroll
    for (int r2 = 0; r2 < 4; ++r2) {
      int row = row0 + w * 16 + grp * 4 + r2;
      Y[(size_t)row * Hn + h] = f2bf((acc[nf][r2] + bv) * scale);
    }
  }
}

// ---------------- kernel 2: flash attention, optional KV split ----------------
// SPLIT=1: grid = 256*nsplit blocks; block (b,s0,split) covers tpb KV tiles,
//          writes unnormalized acc + m + l partials.
// SPLIT=0: grid = 256, direct normalized output (workspace-constrained fallback).
template <int SPLIT>
__global__ __launch_bounds__(256) void attn(const unsigned short* __restrict__ qi,
                                            const unsigned short* __restrict__ ki,
                                            const unsigned short* __restrict__ vi,
                                            float* __restrict__ pacc,
                                            float* __restrict__ pm,
                                            float* __restrict__ pl,
                                            float* __restrict__ out,
                                            int tpb) {
  const int bq    = blockIdx.x & 255;
  const int split = blockIdx.x >> 8;
  const int b  = bq >> 5;
  const int s0 = (bq & 31) * 64;
  const int t0 = split * tpb;
  const unsigned short* Qb = qi + ((size_t)b * Sn + s0) * Hn;
  const unsigned short* Kb = ki + (size_t)b * Sn * Hn;
  const unsigned short* Vb = vi + (size_t)b * Sn * Hn;

  __shared__ __align__(16) unsigned char Ks[64 * 128];       // [key][dim] bf16, swizzled
  __shared__ __align__(16) unsigned char Vt[64 * 128];       // [dim][key] bf16, swizzled
  __shared__ __align__(16) unsigned char Ps[4 * 16 * 128];   // per-wave [16 q][64 key] bf16

  const int tid  = threadIdx.x;
  const int lane = tid & 63;
  const int w    = tid >> 6;
  const int col  = lane & 15;
  const int grp  = lane >> 4;

  bf16x8 qa[2];
#pragma unroll
  for (int ks2 = 0; ks2 < 2; ++ks2)
    qa[ks2] = *(const bf16x8*)(Qb + (size_t)(w * 16 + col) * Hn + ks2 * 32 + grp * 8);

  f32x4 acc[4] = {};
  float m[4], l[4];
#pragma unroll
  for (int r = 0; r < 4; ++r) { m[r] = -1e30f; l[r] = 0.0f; }

  for (int t = t0; t < t0 + tpb; ++t) {
    const unsigned short* Kt = Kb + t * 64 * Hn;
    const unsigned short* Vg = Vb + t * 64 * Hn;
    __syncthreads();  // previous tile fully consumed by all waves
    {
      int kr = tid >> 2, p = tid & 3;
      const uint4* src = (const uint4*)(Kt + kr * Hn);
      uint4 a  = src[p * 2];
      uint4 b2 = src[p * 2 + 1];
      *(uint4*)(Ks + kr * 128 + ((p * 32) ^ ((kr & 7) << 4)))        = a;
      *(uint4*)(Ks + kr * 128 + (((p * 32) + 16) ^ ((kr & 7) << 4))) = b2;
    }
    {
      int kp = tid >> 3;
      int dg = tid & 7;
      uint4 v0 = *(const uint4*)(Vg + (2 * kp) * Hn + dg * 8);
      uint4 v1 = *(const uint4*)(Vg + (2 * kp + 1) * Hn + dg * 8);
      const unsigned short* a0 = (const unsigned short*)&v0;
      const unsigned short* a1 = (const unsigned short*)&v1;
#pragma unroll
      for (int j0 = 0; j0 < 8; ++j0) {
        int j = (j0 + dg) & 7;
        int d = dg * 8 + j;
        unsigned int pk = (unsigned int)a0[j] | ((unsigned int)a1[j] << 16);
        *(unsigned int*)(Vt + d * 128 + ((4 * kp) ^ ((d & 7) << 4))) = pk;
      }
    }
    __syncthreads();
    // S = Q K^T
    f32x4 sf[4] = {};
#pragma unroll
    for (int ks2 = 0; ks2 < 2; ++ks2) {
#pragma unroll
      for (int nf = 0; nf < 4; ++nf) {
        int kr = nf * 16 + col;
        bf16x8 bfr = *(const bf16x8*)(Ks + kr * 128 + ((ks2 * 64 + grp * 16) ^ ((kr & 7) << 4)));
        sf[nf] = __builtin_amdgcn_mfma_f32_16x16x32_bf16(qa[ks2], bfr, sf[nf], 0, 0, 0);
      }
    }
    // online softmax (reduce across 16 lanes of the group)
    float mn[4], fs[4];
#pragma unroll
    for (int r = 0; r < 4; ++r) {
      float mx = fmaxf(fmaxf(sf[0][r], sf[1][r]), fmaxf(sf[2][r], sf[3][r]));
#pragma unroll
      for (int off = 1; off < 16; off <<= 1)
        mx = fmaxf(mx, __shfl_xor(mx, off, 64));
      mn[r] = fmaxf(m[r], mx);
      fs[r] = __expf(m[r] - mn[r]);
      m[r]  = mn[r];
    }
#pragma unroll
    for (int nf = 0; nf < 4; ++nf)
#pragma unroll
      for (int r = 0; r < 4; ++r)
        sf[nf][r] = __expf(sf[nf][r] - mn[r]);
#pragma unroll
    for (int r = 0; r < 4; ++r) {
      float sm = sf[0][r] + sf[1][r] + sf[2][r] + sf[3][r];
#pragma unroll
      for (int off = 1; off < 16; off <<= 1)
        sm += __shfl_xor(sm, off, 64);
      l[r] = l[r] * fs[r] + sm;
    }
#pragma unroll
    for (int nf = 0; nf < 4; ++nf) {
#pragma unroll
      for (int r = 0; r < 4; ++r) {
        acc[nf][r] *= fs[r];
        int prow = grp * 4 + r;
        int key  = nf * 16 + col;
        *(unsigned short*)(Ps + w * 2048 + prow * 128 + ((key * 2) ^ ((prow & 7) << 4))) =
            f2bf(sf[nf][r]);
      }
    }
    // NOTE: no barrier needed — Ps region is per-wave (write->read same wave),
    // Vt protected by the staging barrier above and reuse by loop-top barrier.
#pragma unroll
    for (int kk = 0; kk < 2; ++kk) {
      bf16x8 pa = *(const bf16x8*)(Ps + w * 2048 + col * 128 +
                                   ((kk * 64 + grp * 16) ^ ((col & 7) << 4)));
#pragma unroll
      for (int nf = 0; nf < 4; ++nf) {
        int dr = nf * 16 + col;
        bf16x8 bv = *(const bf16x8*)(Vt + dr * 128 + ((kk * 64 + grp * 16) ^ ((dr & 7) << 4)));
        acc[nf] = __builtin_amdgcn_mfma_f32_16x16x32_bf16(pa, bv, acc[nf], 0, 0, 0);
      }
    }
  }
  // epilogue
  if (SPLIT) {
    const size_t sb = (size_t)split * BS + (size_t)b * Sn;
#pragma unroll
    for (int nf = 0; nf < 4; ++nf) {
#pragma unroll
      for (int r = 0; r < 4; ++r) {
        int row = s0 + w * 16 + grp * 4 + r;
        pacc[(sb + row) * Hn + nf * 16 + col] = acc[nf][r];
      }
    }
    if (col == 0) {
#pragma unroll
      for (int r = 0; r < 4; ++r) {
        int row = s0 + w * 16 + grp * 4 + r;
        pm[sb + row] = m[r];
        pl[sb + row] = l[r];
      }
    }
  } else {
#pragma unroll
    for (int nf = 0; nf < 4; ++nf) {
#pragma unroll
      for (int r = 0; r < 4; ++r) {
        int row = s0 + w * 16 + grp * 4 + r;
        out[((size_t)b * Sn + row) * Hn + nf * 16 + col] = acc[nf][r] / l[r];
      }
    }
  }
}

// ---------------- kernel 3: combine split partials ----------------
// thread = one (row, dim-quad): 16 threads per row, 16384 rows -> 1024 blocks
__global__ __launch_bounds__(256) void combine(const float* __restrict__ pacc,
                                               const float* __restrict__ pm,
                                               const float* __restrict__ pl,
                                               float* __restrict__ out,
                                               int nsplit) {
  int gid = blockIdx.x * 256 + threadIdx.x;
  int gr  = gid >> 4;          // global row in [0, B*S)
  int dq  = (gid & 15) * 4;    // dim quad
  float M = -1e30f;
  for (int s = 0; s < nsplit; ++s) M = fmaxf(M, pm[(size_t)s * BS + gr]);
  float L = 0.0f;
  float4 o = make_float4(0.f, 0.f, 0.f, 0.f);
  for (int s = 0; s < nsplit; ++s) {
    float wgt = __expf(pm[(size_t)s * BS + gr] - M);
    L += pl[(size_t)s * BS + gr] * wgt;
    float4 p = *(const float4*)(pacc + ((size_t)s * BS + gr) * Hn + dq);
    o.x += p.x * wgt; o.y += p.y * wgt; o.z += p.z * wgt; o.w += p.w * wgt;
  }
  float inv = 1.0f / L;
  float4 r = make_float4(o.x * inv, o.y * inv, o.z * inv, o.w * inv);
  *(float4*)(out + (size_t)gr * Hn + dq) = r;
}

extern "C" void kernel_launch(void* const* d_in, const int* in_sizes, int n_in,
                              void* d_out, int out_size, void* d_ws, size_t ws_size,
                              hipStream_t stream) {
  const float* q  = (const float*)d_in[0];
  const float* k  = (const float*)d_in[1];
  const float* v  = (const float*)d_in[2];
  const float* Wq = (const float*)d_in[3];
  const float* bq = (const float*)d_in[4];
  const float* Wk = (const float*)d_in[5];
  const float* bk = (const float*)d_in[6];
  const float* Wv = (const float*)d_in[7];
  const float* bv = (const float*)d_in[8];
  float* out = (float*)d_out;

  unsigned short* Wt = (unsigned short*)d_ws;            // [3][64][768] bf16
  unsigned short* qi = Wt + 3 * Hn * Cn;                 // bf16, pre-scaled by 1/sqrt(C)
  unsigned short* ki = qi + (size_t)BS * Hn;
  unsigned short* vi = ki + (size_t)BS * Hn;
  float* pacc = (float*)(vi + (size_t)BS * Hn);

  const size_t base_bytes = (size_t)(3 * Hn * Cn + 3 * (size_t)BS * Hn) * 2;
  // choose largest split whose partials fit the workspace
  int nsplit = 4;
  while (nsplit > 1 &&
         base_bytes + (size_t)nsplit * ((size_t)BS * Hn * 4 + 2 * (size_t)BS * 4) > ws_size)
    nsplit >>= 1;
  bool direct = (base_bytes + (size_t)nsplit * ((size_t)BS * Hn * 4 + 2 * (size_t)BS * 4) > ws_size);

  float* pm = pacc + (size_t)nsplit * BS * Hn;
  float* pl = pm + (size_t)nsplit * BS;

  wconv<<<dim3((3 * Cn * Hn) / 256), dim3(256), 0, stream>>>(Wq, Wk, Wv, Wt);
  proj<<<dim3(768), dim3(256), 0, stream>>>(q, k, v, bq, bk, bv, Wt, qi, ki, vi);
  if (direct) {
    attn<0><<<dim3(256), dim3(256), 0, stream>>>(qi, ki, vi, nullptr, nullptr, nullptr, out, 32);
  } else {
    attn<1><<<dim3(256 * nsplit), dim3(256), 0, stream>>>(qi, ki, vi, pacc, pm, pl, nullptr,
                                                          32 / nsplit);
    combine<<<dim3(BS * 16 / 256), dim3(256), 0, stream>>>(pacc, pm, pl, out, nsplit);
  }
}

// Round 3
// 86.832 us; speedup vs baseline: 1.2497x; 1.0105x over previous
//
#include <hip/hip_runtime.h>

#define Bn 8
#define Sn 2048
#define Cn 768
#define Hn 64
#define BS (Bn * Sn)

typedef __attribute__((ext_vector_type(8))) short bf16x8;
typedef __attribute__((ext_vector_type(4))) float f32x4;

__device__ __forceinline__ unsigned short f2bf(float x) {
  unsigned int u = __builtin_bit_cast(unsigned int, x);
  u += 0x7FFFu + ((u >> 16) & 1u);
  return (unsigned short)(u >> 16);
}

// ---------------- kernel 0: W convert + transpose: W[c][h] f32 -> Wt[h][c] bf16 ----------------
__global__ __launch_bounds__(256) void wconv(const float* __restrict__ Wq,
                                             const float* __restrict__ Wk,
                                             const float* __restrict__ Wv,
                                             unsigned short* __restrict__ Wt) {
  int idx = blockIdx.x * 256 + threadIdx.x;      // 3*768*64 = 147456 total
  int mat = idx / (Cn * Hn);
  int rem = idx - mat * (Cn * Hn);
  int c = rem / Hn, h = rem - c * Hn;
  const float* W = (mat == 0) ? Wq : (mat == 1) ? Wk : Wv;
  Wt[mat * (Hn * Cn) + h * Cn + c] = f2bf(W[rem]);
}

// ---------------- kernel 1: projections  Y = (X @ W + b) [* scale for q] ----------------
// X streamed global->reg->MFMA (no X LDS: zero reuse). W double-buffered in LDS,
// async-split staging (issue early / ds_write late), ONE barrier per K-chunk of 64.
__global__ __launch_bounds__(256) void proj(const float* __restrict__ q,
                                            const float* __restrict__ k,
                                            const float* __restrict__ v,
                                            const float* __restrict__ bq,
                                            const float* __restrict__ bk,
                                            const float* __restrict__ bv,
                                            const unsigned short* __restrict__ Wt,
                                            unsigned short* __restrict__ qi,
                                            unsigned short* __restrict__ ki,
                                            unsigned short* __restrict__ vi) {
  const int mat  = blockIdx.x >> 8;
  const int row0 = (blockIdx.x & 255) * 64;
  const float* X    = (mat == 0) ? q  : (mat == 1) ? k  : v;
  const float* bias = (mat == 0) ? bq : (mat == 1) ? bk : bv;
  unsigned short* Y = (mat == 0) ? qi : (mat == 1) ? ki : vi;
  const unsigned short* Wm = Wt + mat * (Hn * Cn);
  const float scale = (mat == 0) ? 0.03608439182435161f : 1.0f;  // 1/sqrt(768) folded into qi

  __shared__ __align__(16) unsigned char Wbuf[2][64 * 128];  // [chunk buf][64 cols][64 bf16]

  const int tid  = threadIdx.x;
  const int lane = tid & 63;
  const int w    = tid >> 6;
  const int col  = lane & 15;
  const int grp  = lane >> 4;

  // per-lane X row pointer: lane (col) owns row w*16+col, k-offset grp*8
  const float* Xrow = X + (size_t)(row0 + w * 16 + col) * Cn + grp * 8;
  // W staging ids: thread covers 32B of one W row (col h)
  const int wr_ = tid >> 2;   // 0..63 (output col h)
  const int wp_ = tid & 3;    // 0..3 (16-elem piece)
  const unsigned short* Wrow = Wm + (size_t)wr_ * Cn + wp_ * 16;
  const int wo0 = wr_ * 128 + ((wp_ * 32) ^ ((wr_ & 7) << 4));
  const int wo1 = wr_ * 128 + (((wp_ * 32) + 16) ^ ((wr_ & 7) << 4));

  // ---- prologue: chunk 0 ----
  float4 acur[4], anext[4];
  uint4 wra, wrb;
#pragma unroll
  for (int ks = 0; ks < 2; ++ks) {
    acur[ks * 2]     = *(const float4*)(Xrow + ks * 32);
    acur[ks * 2 + 1] = *(const float4*)(Xrow + ks * 32 + 4);
  }
  wra = *(const uint4*)(Wrow);
  wrb = *(const uint4*)(Wrow + 8);
  *(uint4*)(Wbuf[0] + wo0) = wra;
  *(uint4*)(Wbuf[0] + wo1) = wrb;
  __syncthreads();

  f32x4 acc[4] = {};

  for (int c = 0; c < 12; ++c) {
    // 1) issue next-chunk loads (global->reg), latency hides under compute
    if (c < 11) {
#pragma unroll
      for (int ks = 0; ks < 2; ++ks) {
        anext[ks * 2]     = *(const float4*)(Xrow + (c + 1) * 64 + ks * 32);
        anext[ks * 2 + 1] = *(const float4*)(Xrow + (c + 1) * 64 + ks * 32 + 4);
      }
      wra = *(const uint4*)(Wrow + (c + 1) * 64);
      wrb = *(const uint4*)(Wrow + (c + 1) * 64 + 8);
    }
    // 2) compute chunk c
    const unsigned char* Wb = Wbuf[c & 1];
#pragma unroll
    for (int ks = 0; ks < 2; ++ks) {
      const float4 p0 = acur[ks * 2], p1 = acur[ks * 2 + 1];
      bf16x8 a;
      a[0] = (short)f2bf(p0.x); a[1] = (short)f2bf(p0.y);
      a[2] = (short)f2bf(p0.z); a[3] = (short)f2bf(p0.w);
      a[4] = (short)f2bf(p1.x); a[5] = (short)f2bf(p1.y);
      a[6] = (short)f2bf(p1.z); a[7] = (short)f2bf(p1.w);
#pragma unroll
      for (int nf = 0; nf < 4; ++nf) {
        int wc = nf * 16 + col;
        bf16x8 bfr = *(const bf16x8*)(Wb + wc * 128 + ((ks * 64 + grp * 16) ^ ((wc & 7) << 4)));
        acc[nf] = __builtin_amdgcn_mfma_f32_16x16x32_bf16(a, bfr, acc[nf], 0, 0, 0);
      }
    }
    // 3) write staged W late, single barrier per chunk
    if (c < 11) {
      unsigned char* Wn = Wbuf[(c + 1) & 1];
      *(uint4*)(Wn + wo0) = wra;
      *(uint4*)(Wn + wo1) = wrb;
#pragma unroll
      for (int i = 0; i < 4; ++i) acur[i] = anext[i];
      __syncthreads();
    }
  }

  // epilogue: D layout col = lane&15, row = grp*4 + reg
#pragma unroll
  for (int nf = 0; nf < 4; ++nf) {
    int h = nf * 16 + col;
    float bv = bias[h];
#pragma unroll
    for (int r2 = 0; r2 < 4; ++r2) {
      int row = row0 + w * 16 + grp * 4 + r2;
      Y[(size_t)row * Hn + h] = f2bf((acc[nf][r2] + bv) * scale);
    }
  }
}

// ---------------- kernel 2: flash attention, optional KV split ----------------
template <int SPLIT>
__global__ __launch_bounds__(256) void attn(const unsigned short* __restrict__ qi,
                                            const unsigned short* __restrict__ ki,
                                            const unsigned short* __restrict__ vi,
                                            float* __restrict__ pacc,
                                            float* __restrict__ pm,
                                            float* __restrict__ pl,
                                            float* __restrict__ out,
                                            int tpb) {
  const int bq    = blockIdx.x & 255;
  const int split = blockIdx.x >> 8;
  const int b  = bq >> 5;
  const int s0 = (bq & 31) * 64;
  const int t0 = split * tpb;
  const unsigned short* Qb = qi + ((size_t)b * Sn + s0) * Hn;
  const unsigned short* Kb = ki + (size_t)b * Sn * Hn;
  const unsigned short* Vb = vi + (size_t)b * Sn * Hn;

  __shared__ __align__(16) unsigned char Ks[64 * 128];       // [key][dim] bf16, swizzled
  __shared__ __align__(16) unsigned char Vt[64 * 128];       // [dim][key] bf16, swizzled
  __shared__ __align__(16) unsigned char Ps[4 * 16 * 128];   // per-wave [16 q][64 key] bf16

  const int tid  = threadIdx.x;
  const int lane = tid & 63;
  const int w    = tid >> 6;
  const int col  = lane & 15;
  const int grp  = lane >> 4;

  bf16x8 qa[2];
#pragma unroll
  for (int ks2 = 0; ks2 < 2; ++ks2)
    qa[ks2] = *(const bf16x8*)(Qb + (size_t)(w * 16 + col) * Hn + ks2 * 32 + grp * 8);

  f32x4 acc[4] = {};
  float m[4], l[4];
#pragma unroll
  for (int r = 0; r < 4; ++r) { m[r] = -1e30f; l[r] = 0.0f; }

  for (int t = t0; t < t0 + tpb; ++t) {
    const unsigned short* Kt = Kb + t * 64 * Hn;
    const unsigned short* Vg = Vb + t * 64 * Hn;
    __syncthreads();  // previous tile fully consumed by all waves
    {
      int kr = tid >> 2, p = tid & 3;
      const uint4* src = (const uint4*)(Kt + kr * Hn);
      uint4 a  = src[p * 2];
      uint4 b2 = src[p * 2 + 1];
      *(uint4*)(Ks + kr * 128 + ((p * 32) ^ ((kr & 7) << 4)))        = a;
      *(uint4*)(Ks + kr * 128 + (((p * 32) + 16) ^ ((kr & 7) << 4))) = b2;
    }
    {
      int kp = tid >> 3;
      int dg = tid & 7;
      uint4 v0 = *(const uint4*)(Vg + (2 * kp) * Hn + dg * 8);
      uint4 v1 = *(const uint4*)(Vg + (2 * kp + 1) * Hn + dg * 8);
      const unsigned short* a0 = (const unsigned short*)&v0;
      const unsigned short* a1 = (const unsigned short*)&v1;
#pragma unroll
      for (int j0 = 0; j0 < 8; ++j0) {
        int j = (j0 + dg) & 7;
        int d = dg * 8 + j;
        unsigned int pk = (unsigned int)a0[j] | ((unsigned int)a1[j] << 16);
        *(unsigned int*)(Vt + d * 128 + ((4 * kp) ^ ((d & 7) << 4))) = pk;
      }
    }
    __syncthreads();
    // S = Q K^T
    f32x4 sf[4] = {};
#pragma unroll
    for (int ks2 = 0; ks2 < 2; ++ks2) {
#pragma unroll
      for (int nf = 0; nf < 4; ++nf) {
        int kr = nf * 16 + col;
        bf16x8 bfr = *(const bf16x8*)(Ks + kr * 128 + ((ks2 * 64 + grp * 16) ^ ((kr & 7) << 4)));
        sf[nf] = __builtin_amdgcn_mfma_f32_16x16x32_bf16(qa[ks2], bfr, sf[nf], 0, 0, 0);
      }
    }
    // online softmax
    float mn[4], fs[4];
#pragma unroll
    for (int r = 0; r < 4; ++r) {
      float mx = fmaxf(fmaxf(sf[0][r], sf[1][r]), fmaxf(sf[2][r], sf[3][r]));
#pragma unroll
      for (int off = 1; off < 16; off <<= 1)
        mx = fmaxf(mx, __shfl_xor(mx, off, 64));
      mn[r] = fmaxf(m[r], mx);
      fs[r] = __expf(m[r] - mn[r]);
      m[r]  = mn[r];
    }
#pragma unroll
    for (int nf = 0; nf < 4; ++nf)
#pragma unroll
      for (int r = 0; r < 4; ++r)
        sf[nf][r] = __expf(sf[nf][r] - mn[r]);
#pragma unroll
    for (int r = 0; r < 4; ++r) {
      float sm = sf[0][r] + sf[1][r] + sf[2][r] + sf[3][r];
#pragma unroll
      for (int off = 1; off < 16; off <<= 1)
        sm += __shfl_xor(sm, off, 64);
      l[r] = l[r] * fs[r] + sm;
    }
#pragma unroll
    for (int nf = 0; nf < 4; ++nf) {
#pragma unroll
      for (int r = 0; r < 4; ++r) {
        acc[nf][r] *= fs[r];
        int prow = grp * 4 + r;
        int key  = nf * 16 + col;
        *(unsigned short*)(Ps + w * 2048 + prow * 128 + ((key * 2) ^ ((prow & 7) << 4))) =
            f2bf(sf[nf][r]);
      }
    }
    // per-wave Ps: no cross-wave barrier needed before PV
#pragma unroll
    for (int kk = 0; kk < 2; ++kk) {
      bf16x8 pa = *(const bf16x8*)(Ps + w * 2048 + col * 128 +
                                   ((kk * 64 + grp * 16) ^ ((col & 7) << 4)));
#pragma unroll
      for (int nf = 0; nf < 4; ++nf) {
        int dr = nf * 16 + col;
        bf16x8 bv = *(const bf16x8*)(Vt + dr * 128 + ((kk * 64 + grp * 16) ^ ((dr & 7) << 4)));
        acc[nf] = __builtin_amdgcn_mfma_f32_16x16x32_bf16(pa, bv, acc[nf], 0, 0, 0);
      }
    }
  }
  // epilogue
  if (SPLIT) {
    const size_t sb = (size_t)split * BS + (size_t)b * Sn;
#pragma unroll
    for (int nf = 0; nf < 4; ++nf) {
#pragma unroll
      for (int r = 0; r < 4; ++r) {
        int row = s0 + w * 16 + grp * 4 + r;
        pacc[(sb + row) * Hn + nf * 16 + col] = acc[nf][r];
      }
    }
    if (col == 0) {
#pragma unroll
      for (int r = 0; r < 4; ++r) {
        int row = s0 + w * 16 + grp * 4 + r;
        pm[sb + row] = m[r];
        pl[sb + row] = l[r];
      }
    }
  } else {
#pragma unroll
    for (int nf = 0; nf < 4; ++nf) {
#pragma unroll
      for (int r = 0; r < 4; ++r) {
        int row = s0 + w * 16 + grp * 4 + r;
        out[((size_t)b * Sn + row) * Hn + nf * 16 + col] = acc[nf][r] / l[r];
      }
    }
  }
}

// ---------------- kernel 3: combine split partials ----------------
__global__ __launch_bounds__(256) void combine(const float* __restrict__ pacc,
                                               const float* __restrict__ pm,
                                               const float* __restrict__ pl,
                                               float* __restrict__ out,
                                               int nsplit) {
  int gid = blockIdx.x * 256 + threadIdx.x;
  int gr  = gid >> 4;          // global row in [0, B*S)
  int dq  = (gid & 15) * 4;    // dim quad
  float M = -1e30f;
  for (int s = 0; s < nsplit; ++s) M = fmaxf(M, pm[(size_t)s * BS + gr]);
  float L = 0.0f;
  float4 o = make_float4(0.f, 0.f, 0.f, 0.f);
  for (int s = 0; s < nsplit; ++s) {
    float wgt = __expf(pm[(size_t)s * BS + gr] - M);
    L += pl[(size_t)s * BS + gr] * wgt;
    float4 p = *(const float4*)(pacc + ((size_t)s * BS + gr) * Hn + dq);
    o.x += p.x * wgt; o.y += p.y * wgt; o.z += p.z * wgt; o.w += p.w * wgt;
  }
  float inv = 1.0f / L;
  float4 r = make_float4(o.x * inv, o.y * inv, o.z * inv, o.w * inv);
  *(float4*)(out + (size_t)gr * Hn + dq) = r;
}

extern "C" void kernel_launch(void* const* d_in, const int* in_sizes, int n_in,
                              void* d_out, int out_size, void* d_ws, size_t ws_size,
                              hipStream_t stream) {
  const float* q  = (const float*)d_in[0];
  const float* k  = (const float*)d_in[1];
  const float* v  = (const float*)d_in[2];
  const float* Wq = (const float*)d_in[3];
  const float* bq = (const float*)d_in[4];
  const float* Wk = (const float*)d_in[5];
  const float* bk = (const float*)d_in[6];
  const float* Wv = (const float*)d_in[7];
  const float* bv = (const float*)d_in[8];
  float* out = (float*)d_out;

  unsigned short* Wt = (unsigned short*)d_ws;            // [3][64][768] bf16
  unsigned short* qi = Wt + 3 * Hn * Cn;                 // bf16, pre-scaled by 1/sqrt(C)
  unsigned short* ki = qi + (size_t)BS * Hn;
  unsigned short* vi = ki + (size_t)BS * Hn;
  float* pacc = (float*)(vi + (size_t)BS * Hn);

  const size_t base_bytes = (size_t)(3 * Hn * Cn + 3 * (size_t)BS * Hn) * 2;
  int nsplit = 4;
  while (nsplit > 1 &&
         base_bytes + (size_t)nsplit * ((size_t)BS * Hn * 4 + 2 * (size_t)BS * 4) > ws_size)
    nsplit >>= 1;
  bool direct = (base_bytes + (size_t)nsplit * ((size_t)BS * Hn * 4 + 2 * (size_t)BS * 4) > ws_size);

  float* pm = pacc + (size_t)nsplit * BS * Hn;
  float* pl = pm + (size_t)nsplit * BS;

  wconv<<<dim3((3 * Cn * Hn) / 256), dim3(256), 0, stream>>>(Wq, Wk, Wv, Wt);
  proj<<<dim3(768), dim3(256), 0, stream>>>(q, k, v, bq, bk, bv, Wt, qi, ki, vi);
  if (direct) {
    attn<0><<<dim3(256), dim3(256), 0, stream>>>(qi, ki, vi, nullptr, nullptr, nullptr, out, 32);
  } else {
    attn<1><<<dim3(256 * nsplit), dim3(256), 0, stream>>>(qi, ki, vi, pacc, pm, pl, nullptr,
                                                          32 / nsplit);
    combine<<<dim3(BS * 16 / 256), dim3(256), 0, stream>>>(pacc, pm, pl, out, nsplit);
  }
}